// Round 1
// baseline (1127.608 us; speedup 1.0000x reference)
//
#include <hip/hip_runtime.h>
#include <hip/hip_bf16.h>

// Problem constants
#define DIMD   256
#define NTOK   16384           // 16*1024 tokens
#define NCODE  8192
#define NELEM  (NTOK * DIMD)   // 4194304

// GEMM tiling
#define BM 128                 // token-tile rows
#define BK 128                 // code-tile cols
#define BD 32                  // inner-dim chunk
#define PAD 4                  // LDS pad: stride 132 floats = 528B (16B aligned for b128)
#define LDS_STRIDE (BM + PAD)
#define SPLITS 8
#define KPERSPLIT (NCODE / SPLITS)   // 1024

// -------------------------------------------------------------------------
// Kernel 1: codebook projection  C[k][j] = sum_i E[k][i]*W[j][i] + b[j]
// M=8192 (k), N=256 (j, two 128-tiles), inner=256. Same skeleton as kernel 2.
// -------------------------------------------------------------------------
__global__ __launch_bounds__(256, 3)
void project_kernel(const float* __restrict__ E, const float* __restrict__ W,
                    const float* __restrict__ bias, float* __restrict__ C)
{
    __shared__ float smem[2 * BD * LDS_STRIDE];
    float* As = smem;
    float* Bs = smem + BD * LDS_STRIDE;

    const int tid = threadIdx.x;
    const int tx  = tid & 15;
    const int ty  = tid >> 4;
    const int m0  = blockIdx.x * BM;   // E-row tile
    const int j0  = blockIdx.y * BK;   // output-col tile

    const int srow = tid >> 3;         // 0..31
    const int scol = (tid & 7) * 4;    // 0..28

    float acc[8][8];
#pragma unroll
    for (int i = 0; i < 8; ++i)
#pragma unroll
        for (int j = 0; j < 8; ++j) acc[i][j] = 0.f;

    for (int dc = 0; dc < DIMD / BD; ++dc) {
        const int d0 = dc * BD;
        __syncthreads();
#pragma unroll
        for (int rr = 0; rr < 4; ++rr) {
            const int r = srow + rr * 32;
            float4 av = *(const float4*)&E[(size_t)(m0 + r) * DIMD + d0 + scol];
            As[(scol + 0) * LDS_STRIDE + r] = av.x;
            As[(scol + 1) * LDS_STRIDE + r] = av.y;
            As[(scol + 2) * LDS_STRIDE + r] = av.z;
            As[(scol + 3) * LDS_STRIDE + r] = av.w;
            float4 bv = *(const float4*)&W[(size_t)(j0 + r) * DIMD + d0 + scol];
            Bs[(scol + 0) * LDS_STRIDE + r] = bv.x;
            Bs[(scol + 1) * LDS_STRIDE + r] = bv.y;
            Bs[(scol + 2) * LDS_STRIDE + r] = bv.z;
            Bs[(scol + 3) * LDS_STRIDE + r] = bv.w;
        }
        __syncthreads();
#pragma unroll 4
        for (int d = 0; d < BD; ++d) {
            float4 a0 = *(float4*)&As[d * LDS_STRIDE + ty * 4];
            float4 a1 = *(float4*)&As[d * LDS_STRIDE + 64 + ty * 4];
            float4 b0 = *(float4*)&Bs[d * LDS_STRIDE + tx * 4];
            float4 b1 = *(float4*)&Bs[d * LDS_STRIDE + 64 + tx * 4];
            float a[8] = {a0.x, a0.y, a0.z, a0.w, a1.x, a1.y, a1.z, a1.w};
            float b[8] = {b0.x, b0.y, b0.z, b0.w, b1.x, b1.y, b1.z, b1.w};
#pragma unroll
            for (int i = 0; i < 8; ++i)
#pragma unroll
                for (int j = 0; j < 8; ++j) acc[i][j] = fmaf(a[i], b[j], acc[i][j]);
        }
    }

    float4 bja = *(const float4*)&bias[j0 + tx * 4];
    float4 bjb = *(const float4*)&bias[j0 + 64 + tx * 4];
#pragma unroll
    for (int i = 0; i < 8; ++i) {
        const int mloc = (i < 4) ? (ty * 4 + i) : (64 + ty * 4 + (i - 4));
        const size_t row = (size_t)(m0 + mloc) * DIMD;
        float4 o0 = {acc[i][0] + bja.x, acc[i][1] + bja.y, acc[i][2] + bja.z, acc[i][3] + bja.w};
        float4 o1 = {acc[i][4] + bjb.x, acc[i][5] + bjb.y, acc[i][6] + bjb.z, acc[i][7] + bjb.w};
        *(float4*)&C[row + j0 + tx * 4]      = o0;
        *(float4*)&C[row + j0 + 64 + tx * 4] = o1;
    }
}

// -------------------------------------------------------------------------
// Kernel 2: row sum-of-squares. One wave per row (64 lanes x float4 = 256).
// -------------------------------------------------------------------------
__global__ void rownorm_kernel(const float* __restrict__ A, float* __restrict__ out)
{
    const int wave = threadIdx.x >> 6;
    const int lane = threadIdx.x & 63;
    const int row  = blockIdx.x * 4 + wave;
    float4 v = *(const float4*)&A[(size_t)row * DIMD + lane * 4];
    float s = v.x * v.x + v.y * v.y + v.z * v.z + v.w * v.w;
#pragma unroll
    for (int off = 1; off < 64; off <<= 1) s += __shfl_xor(s, off);
    if (lane == 0) out[row] = s;
}

// -------------------------------------------------------------------------
// Kernel 3: the big one. d[n,k] = xn[n] + cn[k] - 2*dot(x_n, c_k), fused
// running argmin. grid (NTOK/BM, SPLITS); each block scans KPERSPLIT codes.
// Tie-break: lowest k everywhere (matches np.argmin).
// -------------------------------------------------------------------------
__global__ __launch_bounds__(256, 3)
void dist_argmin_kernel(const float* __restrict__ X, const float* __restrict__ C,
                        const float* __restrict__ xnorm, const float* __restrict__ cnorm,
                        float* __restrict__ pval, int* __restrict__ pidx)
{
    __shared__ float smem[2 * BD * LDS_STRIDE];   // 33792 B
    float* Xs = smem;
    float* Cs = smem + BD * LDS_STRIDE;

    const int tid   = threadIdx.x;
    const int tx    = tid & 15;
    const int ty    = tid >> 4;
    const int m0    = blockIdx.x * BM;
    const int split = blockIdx.y;
    const int kbase = split * KPERSPLIT;

    const int srow = tid >> 3;
    const int scol = (tid & 7) * 4;

    float xn[8];
#pragma unroll
    for (int i = 0; i < 4; ++i) {
        xn[i]     = xnorm[m0 + ty * 4 + i];
        xn[i + 4] = xnorm[m0 + 64 + ty * 4 + i];
    }

    float runv[8];
    int   runi[8];
#pragma unroll
    for (int i = 0; i < 8; ++i) { runv[i] = 3.4e38f; runi[i] = 0x7fffffff; }

    for (int kt = 0; kt < KPERSPLIT / BK; ++kt) {
        const int k0 = kbase + kt * BK;
        float acc[8][8];
#pragma unroll
        for (int i = 0; i < 8; ++i)
#pragma unroll
            for (int j = 0; j < 8; ++j) acc[i][j] = 0.f;

        for (int dc = 0; dc < DIMD / BD; ++dc) {
            const int d0 = dc * BD;
            __syncthreads();
#pragma unroll
            for (int rr = 0; rr < 4; ++rr) {
                const int r = srow + rr * 32;
                float4 xv = *(const float4*)&X[(size_t)(m0 + r) * DIMD + d0 + scol];
                Xs[(scol + 0) * LDS_STRIDE + r] = xv.x;
                Xs[(scol + 1) * LDS_STRIDE + r] = xv.y;
                Xs[(scol + 2) * LDS_STRIDE + r] = xv.z;
                Xs[(scol + 3) * LDS_STRIDE + r] = xv.w;
                float4 cv = *(const float4*)&C[(size_t)(k0 + r) * DIMD + d0 + scol];
                Cs[(scol + 0) * LDS_STRIDE + r] = cv.x;
                Cs[(scol + 1) * LDS_STRIDE + r] = cv.y;
                Cs[(scol + 2) * LDS_STRIDE + r] = cv.z;
                Cs[(scol + 3) * LDS_STRIDE + r] = cv.w;
            }
            __syncthreads();
#pragma unroll 4
            for (int d = 0; d < BD; ++d) {
                float4 a0 = *(float4*)&Xs[d * LDS_STRIDE + ty * 4];
                float4 a1 = *(float4*)&Xs[d * LDS_STRIDE + 64 + ty * 4];
                float4 b0 = *(float4*)&Cs[d * LDS_STRIDE + tx * 4];
                float4 b1 = *(float4*)&Cs[d * LDS_STRIDE + 64 + tx * 4];
                float a[8] = {a0.x, a0.y, a0.z, a0.w, a1.x, a1.y, a1.z, a1.w};
                float b[8] = {b0.x, b0.y, b0.z, b0.w, b1.x, b1.y, b1.z, b1.w};
#pragma unroll
                for (int i = 0; i < 8; ++i)
#pragma unroll
                    for (int j = 0; j < 8; ++j) acc[i][j] = fmaf(a[i], b[j], acc[i][j]);
            }
        }

        // running-min update, ascending k inside the thread
        float cn[8];
#pragma unroll
        for (int j = 0; j < 4; ++j) {
            cn[j]     = cnorm[k0 + tx * 4 + j];
            cn[j + 4] = cnorm[k0 + 64 + tx * 4 + j];
        }
#pragma unroll
        for (int i = 0; i < 8; ++i) {
#pragma unroll
            for (int j = 0; j < 8; ++j) {
                const int k = k0 + ((j < 4) ? (tx * 4 + j) : (64 + tx * 4 + (j - 4)));
                const float v = fmaf(-2.f, acc[i][j], xn[i] + cn[j]);
                if (v < runv[i]) { runv[i] = v; runi[i] = k; }
            }
        }
    }

    // cross-tx reduction through LDS (reuse staging buffer)
    __syncthreads();
    float* scr_v = smem;                  // [128][16]
    int*   scr_i = (int*)(smem + 2048);   // [128][16]
#pragma unroll
    for (int i = 0; i < 8; ++i) {
        const int mloc = (i < 4) ? (ty * 4 + i) : (64 + ty * 4 + (i - 4));
        scr_v[mloc * 16 + tx] = runv[i];
        scr_i[mloc * 16 + tx] = runi[i];
    }
    __syncthreads();
    if (tid < BM) {
        float bv = scr_v[tid * 16];
        int   bi = scr_i[tid * 16];
        for (int t = 1; t < 16; ++t) {
            const float v = scr_v[tid * 16 + t];
            const int  ii = scr_i[tid * 16 + t];
            if (v < bv || (v == bv && ii < bi)) { bv = v; bi = ii; }
        }
        pval[(size_t)(m0 + tid) * SPLITS + split] = bv;
        pidx[(size_t)(m0 + tid) * SPLITS + split] = bi;
    }
}

// -------------------------------------------------------------------------
// Kernel 4: combine splits, gather codebook row, straight-through output,
// loss accumulation. One wave per token.
// -------------------------------------------------------------------------
__global__ void finalize_kernel(const float* __restrict__ X, const float* __restrict__ C,
                                const float* __restrict__ pval, const int* __restrict__ pidx,
                                float* __restrict__ out)
{
    const int t    = blockIdx.x;
    const int lane = threadIdx.x;   // 64 threads

    int bi = 0;
    if (lane == 0) {
        float bv = pval[(size_t)t * SPLITS];
        bi = pidx[(size_t)t * SPLITS];
        for (int s = 1; s < SPLITS; ++s) {
            const float v = pval[(size_t)t * SPLITS + s];
            const int  ii = pidx[(size_t)t * SPLITS + s];
            if (v < bv || (v == bv && ii < bi)) { bv = v; bi = ii; }
        }
    }
    bi = __shfl(bi, 0);

    float4 c4 = *(const float4*)&C[(size_t)bi * DIMD + lane * 4];
    float4 x4 = *(const float4*)&X[(size_t)t * DIMD + lane * 4];
    float4 w  = {c4.x - x4.x, c4.y - x4.y, c4.z - x4.z, c4.w - x4.w};
    float ssq = w.x * w.x + w.y * w.y + w.z * w.z + w.w * w.w;
#pragma unroll
    for (int off = 1; off < 64; off <<= 1) ssq += __shfl_xor(ssq, off);

    // straight-through: out = x + (zq - x), matching the reference's rounding
    float4 zq = {x4.x + w.x, x4.y + w.y, x4.z + w.z, x4.w + w.w};
    *(float4*)&out[(size_t)t * DIMD + lane * 4] = zq;

    if (lane == 0) {
        // diff = mean((zq-x)^2) + 0.25*mean((zq-x)^2) = 1.25 * mse
        atomicAdd(&out[NELEM], ssq * (1.25f / (float)NELEM));
        out[NELEM + 1 + t] = (float)bi;
    }
}

// -------------------------------------------------------------------------
extern "C" void kernel_launch(void* const* d_in, const int* in_sizes, int n_in,
                              void* d_out, int out_size, void* d_ws, size_t ws_size,
                              hipStream_t stream)
{
    const float* X = (const float*)d_in[0];   // [16,1024,256]
    const float* E = (const float*)d_in[1];   // [8192,256]
    const float* W = (const float*)d_in[2];   // [256,256]
    const float* b = (const float*)d_in[3];   // [256]
    float* out = (float*)d_out;

    float* ws    = (float*)d_ws;
    float* C     = ws;                          // 8192*256 floats
    float* cnorm = C + (size_t)NCODE * DIMD;    // 8192
    float* xnorm = cnorm + NCODE;               // 16384
    float* pval  = xnorm + NTOK;                // 16384*8
    int*   pidx  = (int*)(pval + (size_t)NTOK * SPLITS);

    // zero the loss accumulator (d_out is poisoned 0xAA before each call)
    hipMemsetAsync(out + NELEM, 0, sizeof(float), stream);

    project_kernel<<<dim3(NCODE / BM, DIMD / BK), 256, 0, stream>>>(E, W, b, C);
    rownorm_kernel<<<NTOK / 4, 256, 0, stream>>>(X, xnorm);
    rownorm_kernel<<<NCODE / 4, 256, 0, stream>>>(C, cnorm);
    dist_argmin_kernel<<<dim3(NTOK / BM, SPLITS), 256, 0, stream>>>(X, C, xnorm, cnorm, pval, pidx);
    finalize_kernel<<<NTOK, 64, 0, stream>>>(X, C, pval, pidx, out);
}